// Round 1
// baseline (85.754 us; speedup 1.0000x reference)
//
#include <hip/hip_runtime.h>
#include <hip/hip_bf16.h>

typedef unsigned int uint32;
typedef unsigned short u16;

#define NPT 128        // grid nodes per dim
#define RNK 16         // TT rank
#define MIDROW 264     // bf16 elems per LDS row for mid core (256 + 8 pad) = 528 B
#define MIDROW_U32 132
#define EROW 24        // bf16 elems per edge row (16 + 8 pad) = 48 B
// 67584 (mid) + 2*6144 (edges) = 79872 B -> 2 blocks/CU (159744 <= 163840)
#define SMEM_BYTES (NPT*MIDROW*2 + 2*NPT*EROW*2)

#if defined(__has_builtin)
#if __has_builtin(__builtin_amdgcn_fdot2_f32_bf16)
#define HAVE_BFDOT2 1
#endif
#endif

__device__ __forceinline__ float bl(uint32 u){ return __uint_as_float(u << 16); }
__device__ __forceinline__ float bh(uint32 u){ return __uint_as_float(u & 0xffff0000u); }

__device__ __forceinline__ uint32 pk2(float a, float b){
  __hip_bfloat16 l = __float2bfloat16(a);
  __hip_bfloat16 h = __float2bfloat16(b);
  return (uint32)(*(u16*)&l) | ((uint32)(*(u16*)&h) << 16);
}

#ifdef HAVE_BFDOT2
typedef __bf16 v2bf __attribute__((ext_vector_type(2)));
__device__ __forceinline__ v2bf bc(uint32 u){ return __builtin_bit_cast(v2bf, u); }

// dot of packed-bf16 v (8 u32) with 16 bf16 core elems in two uint4
__device__ __forceinline__ float dot16b(const uint32* vp, uint4 U0, uint4 U1) {
  float s0 = 0.f, s1 = 0.f;
  s0 = __builtin_amdgcn_fdot2_f32_bf16(bc(vp[0]), bc(U0.x), s0, false);
  s0 = __builtin_amdgcn_fdot2_f32_bf16(bc(vp[1]), bc(U0.y), s0, false);
  s0 = __builtin_amdgcn_fdot2_f32_bf16(bc(vp[2]), bc(U0.z), s0, false);
  s0 = __builtin_amdgcn_fdot2_f32_bf16(bc(vp[3]), bc(U0.w), s0, false);
  s1 = __builtin_amdgcn_fdot2_f32_bf16(bc(vp[4]), bc(U1.x), s1, false);
  s1 = __builtin_amdgcn_fdot2_f32_bf16(bc(vp[5]), bc(U1.y), s1, false);
  s1 = __builtin_amdgcn_fdot2_f32_bf16(bc(vp[6]), bc(U1.z), s1, false);
  s1 = __builtin_amdgcn_fdot2_f32_bf16(bc(vp[7]), bc(U1.w), s1, false);
  return s0 + s1;
}
#else
// fallback: unpack + fmaf
__device__ __forceinline__ float dot16(const float* v, uint4 U0, uint4 U1) {
  float s0 = fmaf(v[1],  bh(U0.x), v[0]*bl(U0.x));
  s0 = fmaf(v[2],  bl(U0.y), s0); s0 = fmaf(v[3],  bh(U0.y), s0);
  float s1 = fmaf(v[5],  bh(U0.z), v[4]*bl(U0.z));
  s1 = fmaf(v[6],  bl(U0.w), s1); s1 = fmaf(v[7],  bh(U0.w), s1);
  float s2 = fmaf(v[9],  bh(U1.x), v[8]*bl(U1.x));
  s2 = fmaf(v[10], bl(U1.y), s2); s2 = fmaf(v[11], bh(U1.y), s2);
  float s3 = fmaf(v[13], bh(U1.z), v[12]*bl(U1.z));
  s3 = fmaf(v[14], bl(U1.w), s3); s3 = fmaf(v[15], bh(U1.w), s3);
  return (s0 + s1) + (s2 + s3);
}
#endif

// lerp 8 bf16 pairs (lo,hi packed in uint4) -> fp32
__device__ __forceinline__ void lerp8(uint4 lo, uint4 hi, float w, float* o) {
  o[0] = fmaf(w, bl(hi.x) - bl(lo.x), bl(lo.x));
  o[1] = fmaf(w, bh(hi.x) - bh(lo.x), bh(lo.x));
  o[2] = fmaf(w, bl(hi.y) - bl(lo.y), bl(lo.y));
  o[3] = fmaf(w, bh(hi.y) - bh(lo.y), bh(lo.y));
  o[4] = fmaf(w, bl(hi.z) - bl(lo.z), bl(lo.z));
  o[5] = fmaf(w, bh(hi.z) - bh(lo.z), bh(lo.z));
  o[6] = fmaf(w, bl(hi.w) - bl(lo.w), bl(lo.w));
  o[7] = fmaf(w, bh(hi.w) - bh(lo.w), bh(lo.w));
}

// Stage one mid core: global [i][n][j] fp32 -> LDS [n][j*16+i] bf16, ds_write_b128.
// chunk t in [0,4096): n=t>>5, j=(t>>1)&15, h=t&1 (i-octet). Write banks are
// exactly uniform: start bank = 4(n+2j+h) mod 32 cycles over all 8 groups per wave.
__device__ __forceinline__ void stage_mid(const float* __restrict__ g, u16* dst) {
#pragma unroll
  for (int c = 0; c < 4; ++c) {
    int t = (int)threadIdx.x + c * 1024;
    int n = t >> 5;
    int j = (t >> 1) & 15;
    int h = t & 1;
    const float* s = g + h * 8 * 2048 + n * 16 + j;   // i = 8h+k, stride 2048 floats
    uint4 wv;
    wv.x = pk2(s[0],        s[2048]);
    wv.y = pk2(s[2 * 2048], s[3 * 2048]);
    wv.z = pk2(s[4 * 2048], s[5 * 2048]);
    wv.w = pk2(s[6 * 2048], s[7 * 2048]);
    *(uint4*)(dst + n * MIDROW + j * 16 + h * 8) = wv;
  }
}

__device__ __forceinline__ float remap_clamp(float x) {
  float xr = (x + 1.0f) * 0.5f * (float)(NPT - 1);
  return fminf(fmaxf(xr, 0.0f), (float)(NPT - 1));
}

// 2 threads per point (lane q pairs with lane q+32; each owns 8 of 16 j-outputs).
// LDS holds ONE mid core at a time (c1 -> compute dims0-1 -> restage c2 -> dims2-3),
// halving LDS to 79.9 KB so 2 blocks (32 waves) fit per CU.
__global__ __launch_bounds__(1024, 8) void tt_kernel(
    const float* __restrict__ x,  const float* __restrict__ g0,
    const float* __restrict__ g1, const float* __restrict__ g2,
    const float* __restrict__ g3, float* __restrict__ out, int npts)
{
  extern __shared__ char smem[];
  u16* mid = (u16*)smem;            // [128][264] bf16, reused for core1 then core2
  u16* e0  = mid + NPT * MIDROW;    // [128][24] bf16 (16 data + 8 pad)
  u16* e3  = e0 + NPT * EROW;       // [128][24] bf16

  // ---- phase 0: stage core1 + edge cores ----
  stage_mid(g1, mid);
  if (threadIdx.x < 512) {
    int t = (int)threadIdx.x;
    if (t < 256) {                  // core0: [1][n][j] contiguous
      int n = t >> 1, h = t & 1;
      const float4* s = (const float4*)(g0 + n * 16 + h * 8);
      float4 a = s[0], b = s[1];
      uint4 wv = make_uint4(pk2(a.x, a.y), pk2(a.z, a.w), pk2(b.x, b.y), pk2(b.z, b.w));
      *(uint4*)(e0 + n * EROW + h * 8) = wv;
    } else {                        // core3: [i][n][1] -> row n holds i=0..15
      t -= 256;
      int n = t >> 1, h = t & 1;
      const float* s = g3 + h * 8 * NPT + n;
      uint4 wv = make_uint4(pk2(s[0],       s[NPT]),     pk2(s[2 * NPT], s[3 * NPT]),
                            pk2(s[4 * NPT], s[5 * NPT]), pk2(s[6 * NPT], s[7 * NPT]));
      *(uint4*)(e3 + n * EROW + h * 8) = wv;
    }
  }
  __syncthreads();

  const int lane = (int)threadIdx.x & 63;
  const int wid  = (int)threadIdx.x >> 6;
  const int half = lane >> 5;                        // 0: j 0-7, 1: j 8-15
  const int p    = (int)blockIdx.x * 512 + wid * 32 + (lane & 31);
  const bool active = p < npts;
  float4 xv = active ? reinterpret_cast<const float4*>(x)[p]
                     : make_float4(-1.f, -1.f, -1.f, -1.f);

  // ---- dim 0: lerp core0 row -> v[16] (both halves compute full v) ----
  float v[16];
  {
    float xc = remap_clamp(xv.x);
    int n0 = (int)xc; float w = xc - (float)n0; int n1 = min(n0 + 1, NPT - 1);
    const uint4* L = (const uint4*)(e0 + n0 * EROW);
    const uint4* H = (const uint4*)(e0 + n1 * EROW);
    uint4 l0 = L[0], l1 = L[1], h0 = H[0], h1 = H[1];
    lerp8(l0, h0, w, v);
    lerp8(l1, h1, w, v + 8);
  }

  float nv[8];
  // ---- dim 1: this half's 8 j-outputs ----
  {
#ifdef HAVE_BFDOT2
    uint32 vp[8];
#pragma unroll
    for (int k = 0; k < 8; ++k) vp[k] = pk2(v[2 * k], v[2 * k + 1]);
#endif
    float xc = remap_clamp(xv.y);
    int n0 = (int)xc; float w = xc - (float)n0; int n1 = min(n0 + 1, NPT - 1);
    const uint32* r0 = (const uint32*)mid + n0 * MIDROW_U32 + (half << 6);
    const uint32* r1 = (const uint32*)mid + n1 * MIDROW_U32 + (half << 6);
#pragma unroll
    for (int jj = 0; jj < 8; ++jj) {
      const uint4* p0 = (const uint4*)(r0 + jj * 8);
      const uint4* p1 = (const uint4*)(r1 + jj * 8);
      uint4 A0 = p0[0], A1 = p0[1], B0 = p1[0], B1 = p1[1];
#ifdef HAVE_BFDOT2
      float a = dot16b(vp, A0, A1);
      float b = dot16b(vp, B0, B1);
#else
      float a = dot16(v, A0, A1);
      float b = dot16(v, B0, B1);
#endif
      nv[jj] = fmaf(w, b - a, a);
    }
  }
  // exchange halves -> full v[16] (static indices, cndmask select)
#pragma unroll
  for (int k = 0; k < 8; ++k) {
    float ov = __shfl_xor(nv[k], 32, 64);
    v[k]     = half ? ov    : nv[k];
    v[8 + k] = half ? nv[k] : ov;
  }

  // ---- restage: core2 into the same LDS buffer ----
  __syncthreads();            // all waves done reading core1
  stage_mid(g2, mid);
  __syncthreads();

  // ---- dim 2 ----
  {
#ifdef HAVE_BFDOT2
    uint32 vp[8];
#pragma unroll
    for (int k = 0; k < 8; ++k) vp[k] = pk2(v[2 * k], v[2 * k + 1]);
#endif
    float xc = remap_clamp(xv.z);
    int n0 = (int)xc; float w = xc - (float)n0; int n1 = min(n0 + 1, NPT - 1);
    const uint32* r0 = (const uint32*)mid + n0 * MIDROW_U32 + (half << 6);
    const uint32* r1 = (const uint32*)mid + n1 * MIDROW_U32 + (half << 6);
#pragma unroll
    for (int jj = 0; jj < 8; ++jj) {
      const uint4* p0 = (const uint4*)(r0 + jj * 8);
      const uint4* p1 = (const uint4*)(r1 + jj * 8);
      uint4 A0 = p0[0], A1 = p0[1], B0 = p1[0], B1 = p1[1];
#ifdef HAVE_BFDOT2
      float a = dot16b(vp, A0, A1);
      float b = dot16b(vp, B0, B1);
#else
      float a = dot16(v, A0, A1);
      float b = dot16(v, B0, B1);
#endif
      nv[jj] = fmaf(w, b - a, a);
    }
  }

  // ---- dim 3: half-split dot (no exchange needed; nv[k] pairs with core3 i=half*8+k) ----
  float acc = 0.f;
  {
    float xc = remap_clamp(xv.w);
    int n0 = (int)xc; float w = xc - (float)n0; int n1 = min(n0 + 1, NPT - 1);
    uint4 lo = *(const uint4*)(e3 + n0 * EROW + half * 8);
    uint4 hi = *(const uint4*)(e3 + n1 * EROW + half * 8);
    float c3v[8];
    lerp8(lo, hi, w, c3v);
#pragma unroll
    for (int k = 0; k < 8; ++k) acc = fmaf(nv[k], c3v[k], acc);
  }
  acc += __shfl_xor(acc, 32, 64);
  if (active && half == 0) out[p] = acc;
}

extern "C" void kernel_launch(void* const* d_in, const int* in_sizes, int n_in,
                              void* d_out, int out_size, void* d_ws, size_t ws_size,
                              hipStream_t stream) {
  const float* x  = (const float*)d_in[0];
  const float* g0 = (const float*)d_in[1];
  const float* g1 = (const float*)d_in[2];
  const float* g2 = (const float*)d_in[3];
  const float* g3 = (const float*)d_in[4];
  float* out = (float*)d_out;

  int B = in_sizes[0] / 4;
  hipFuncSetAttribute(reinterpret_cast<const void*>(tt_kernel),
                      hipFuncAttributeMaxDynamicSharedMemorySize, SMEM_BYTES);
  int block = 1024;
  int grid = (2 * B + block - 1) / block;   // 2 threads/point -> 512 blocks, 2/CU
  tt_kernel<<<grid, block, SMEM_BYTES, stream>>>(x, g0, g1, g2, g3, out, B);
}